// Round 1
// baseline (670.966 us; speedup 1.0000x reference)
//
#include <hip/hip_runtime.h>
#include <hip/hip_bf16.h>
#include <math.h>

#define EPS 1e-6f
#define NSINK 1024
#define NSRC 4096
#define DIM 512
#define NH 8
#define HD 64
#define BATCH 2
// fold (d^-0.5 = 1/8) * log2(e) into q so sim exp is a single exp2
#define QSCALE 0.18033688011112042f

__device__ inline float fast_exp2(float x) {
#if __has_builtin(__builtin_amdgcn_exp2f)
    return __builtin_amdgcn_exp2f(x);
#else
    return exp2f(x);
#endif
}

// ---------------- LayerNorm (row = 512) ----------------
__global__ __launch_bounds__(256) void ln_kernel(const float* __restrict__ x,
    const float* __restrict__ g, const float* __restrict__ be,
    float* __restrict__ y)
{
    int row = blockIdx.x;
    int t = threadIdx.x;
    const float* xr = x + (size_t)row * DIM;
    float v0 = xr[t], v1 = xr[t + 256];
    float s = v0 + v1, sq = v0 * v0 + v1 * v1;
    #pragma unroll
    for (int off = 32; off > 0; off >>= 1) {
        s  += __shfl_down(s, off, 64);
        sq += __shfl_down(sq, off, 64);
    }
    __shared__ float rs[4], rq[4];
    int wave = t >> 6;
    if ((t & 63) == 0) { rs[wave] = s; rq[wave] = sq; }
    __syncthreads();
    s  = rs[0] + rs[1] + rs[2] + rs[3];
    sq = rq[0] + rq[1] + rq[2] + rq[3];
    float mu = s * (1.0f / DIM);
    float var = sq * (1.0f / DIM) - mu * mu;
    float a = var + EPS;
    float r = rsqrtf(a);
    r = r * (1.5f - 0.5f * a * r * r);   // Newton refine
    float* yr = y + (size_t)row * DIM;
    yr[t]       = (v0 - mu) * r * g[t] + be[t];
    yr[t + 256] = (v1 - mu) * r * g[t + 256] + be[t + 256];
}

// ---------------- generic 64x64x16 f32 GEMM, 256 thr, 4x4 micro ----------------
// MODE 1: C = (A@B + bias) * QSCALE scattered to q[b,h,i,d]
// MODE 2: C = A@B + bias scattered to k[b,h,j,d] (n<512) / v[b,h,j,d] (n>=512)
// MODE 3: A-prologue: a = (pv0 + pv1 + EPS*vsum) / (rs0+rs1+NSRC*EPS); C = A@B+bias row-major (d_out)
template<int MODE>
__global__ __launch_bounds__(256) void gemm64(
    const float* __restrict__ A, const float* __restrict__ B,
    const float* __restrict__ bias, float* __restrict__ C0, float* __restrict__ C1,
    int M, int N, int K,
    const float* __restrict__ pv1, const float* __restrict__ vsumb,
    const float* __restrict__ rsum0, const float* __restrict__ rsum1)
{
    __shared__ alignas(16) float As[16][64];
    __shared__ alignas(16) float Bs[16][64];
    int t = threadIdx.x;
    int tr = t >> 4, tc = t & 15;
    int n0 = blockIdx.x * 64, m0 = blockIdx.y * 64;
    float acc[4][4] = {};
    int arow = t >> 2, aseg = t & 3;
    int bk = t >> 4, bcol = (t & 15) * 4;

    for (int k0 = 0; k0 < K; k0 += 16) {
        float4 av = *(const float4*)(A + (size_t)(m0 + arow) * K + k0 + aseg * 4);
        if (MODE == 3) {
            int m = m0 + arow;
            int b = m >> 10, i = m & 1023;
            int kidx = k0 + aseg * 4;
            int h = kidx >> 6;
            int bh = b * NH + h;
            float rsv = rsum0[bh * NSINK + i] + rsum1[bh * NSINK + i] + (float)NSRC * EPS;
            float inv = 1.0f / rsv;
            const float* p1 = pv1 + (size_t)m * DIM + kidx;
            const float* vs = vsumb + bh * HD + (kidx & 63);
            av.x = (av.x + p1[0] + EPS * vs[0]) * inv;
            av.y = (av.y + p1[1] + EPS * vs[1]) * inv;
            av.z = (av.z + p1[2] + EPS * vs[2]) * inv;
            av.w = (av.w + p1[3] + EPS * vs[3]) * inv;
        }
        As[aseg*4+0][arow] = av.x;
        As[aseg*4+1][arow] = av.y;
        As[aseg*4+2][arow] = av.z;
        As[aseg*4+3][arow] = av.w;
        *(float4*)&Bs[bk][bcol] = *(const float4*)(B + (size_t)(k0 + bk) * N + n0 + bcol);
        __syncthreads();
        #pragma unroll
        for (int kk = 0; kk < 16; ++kk) {
            float4 af = *(const float4*)&As[kk][tr*4];
            float4 bf = *(const float4*)&Bs[kk][tc*4];
            float a_[4] = {af.x, af.y, af.z, af.w};
            float b_[4] = {bf.x, bf.y, bf.z, bf.w};
            #pragma unroll
            for (int r = 0; r < 4; ++r)
                #pragma unroll
                for (int c = 0; c < 4; ++c)
                    acc[r][c] += a_[r] * b_[c];
        }
        __syncthreads();
    }

    #pragma unroll
    for (int r = 0; r < 4; ++r) {
        int m = m0 + tr*4 + r;
        #pragma unroll
        for (int c = 0; c < 4; ++c) {
            int n = n0 + tc*4 + c;
            float val = acc[r][c] + bias[n];
            if (MODE == 1) {
                int b = m >> 10, i = m & 1023;
                int h = n >> 6, d = n & 63;
                C0[((size_t)(b*NH + h) * NSINK + i) * HD + d] = val * QSCALE;
            } else if (MODE == 2) {
                int b = m >> 12, j = m & 4095;
                float* dst = C0; int nn = n;
                if (n >= DIM) { dst = C1; nn = n - DIM; }
                int h = nn >> 6, d = nn & 63;
                dst[((size_t)(b*NH + h) * NSRC + j) * HD + d] = val;
            } else {
                C0[(size_t)m * N + n] = val;
            }
        }
    }
}

// ---------------- vsum = sum_j v[b,h,j,:] ----------------
__global__ __launch_bounds__(256) void vsum_part(const float* __restrict__ v, float* __restrict__ part)
{
    int c = blockIdx.x, bh = blockIdx.y;
    int t = threadIdx.x;
    int d = t & 63, s = t >> 6;
    const float* vb = v + (size_t)bh * NSRC * HD;
    float a = 0.f;
    for (int j = c * 512 + s; j < c * 512 + 512; j += 4)
        a += vb[(size_t)j * HD + d];
    __shared__ float red[4][64];
    red[s][d] = a;
    __syncthreads();
    if (t < 64) part[((size_t)bh * 8 + c) * HD + t]
        = red[0][t] + red[1][t] + red[2][t] + red[3][t];
}

__global__ void vsum_fin(const float* __restrict__ part, float* __restrict__ vs)
{
    int t = threadIdx.x;          // 1024 threads
    int bh = t >> 6;
    float a = 0.f;
    #pragma unroll
    for (int c = 0; c < 8; ++c) a += part[((size_t)bh * 8 + c) * HD + (t & 63)];
    vs[t] = a;
}

// ---------------- pass A: colsum[b,h,j] = sum_i exp2(q'.k) ----------------
// grid (32 j-tiles, 16 bh), 256 thr, 128x128 tile, 8x8 micro
__global__ __launch_bounds__(256) void pass_a(
    const float* __restrict__ q, const float* __restrict__ kbuf,
    float* __restrict__ colsum)
{
    int bh = blockIdx.y;
    int j0 = blockIdx.x * 128;
    int t = threadIdx.x;
    int tr = t >> 4, tc = t & 15;
    __shared__ alignas(16) float Qs[16][128];
    __shared__ alignas(16) float Ks[16][128];
    const float* qb = q + (size_t)bh * NSINK * HD;
    const float* kb = kbuf + (size_t)bh * NSRC * HD;
    float csum[8] = {};

    for (int i0 = 0; i0 < NSINK; i0 += 128) {
        float acc[8][8] = {};
        for (int kc = 0; kc < HD; kc += 16) {
            #pragma unroll
            for (int l = 0; l < 2; ++l) {
                int fid = t + l * 256;
                int row = fid >> 2, seg = fid & 3;
                float4 v = *(const float4*)&qb[(size_t)(i0 + row) * HD + kc + seg * 4];
                Qs[seg*4+0][row] = v.x; Qs[seg*4+1][row] = v.y;
                Qs[seg*4+2][row] = v.z; Qs[seg*4+3][row] = v.w;
                float4 w = *(const float4*)&kb[(size_t)(j0 + row) * HD + kc + seg * 4];
                Ks[seg*4+0][row] = w.x; Ks[seg*4+1][row] = w.y;
                Ks[seg*4+2][row] = w.z; Ks[seg*4+3][row] = w.w;
            }
            __syncthreads();
            #pragma unroll
            for (int kk = 0; kk < 16; ++kk) {
                float4 a0 = *(const float4*)&Qs[kk][tr*8];
                float4 a1 = *(const float4*)&Qs[kk][tr*8+4];
                float4 b0 = *(const float4*)&Ks[kk][tc*8];
                float4 b1 = *(const float4*)&Ks[kk][tc*8+4];
                float a_[8] = {a0.x,a0.y,a0.z,a0.w,a1.x,a1.y,a1.z,a1.w};
                float b_[8] = {b0.x,b0.y,b0.z,b0.w,b1.x,b1.y,b1.z,b1.w};
                #pragma unroll
                for (int r = 0; r < 8; ++r)
                    #pragma unroll
                    for (int c = 0; c < 8; ++c)
                        acc[r][c] += a_[r] * b_[c];
            }
            __syncthreads();
        }
        #pragma unroll
        for (int c = 0; c < 8; ++c) {
            float s = 0.f;
            #pragma unroll
            for (int r = 0; r < 8; ++r) s += fast_exp2(acc[r][c]);
            csum[c] += s;
        }
    }
    __syncthreads();
    float* red = &Qs[0][0];  // [16][128]
    #pragma unroll
    for (int c = 0; c < 8; ++c) red[tr * 128 + tc * 8 + c] = csum[c];
    __syncthreads();
    if (t < 128) {
        float s = 0.f;
        #pragma unroll
        for (int w = 0; w < 16; ++w) s += red[w * 128 + t];
        colsum[(size_t)bh * NSRC + j0 + t] = s;
    }
}

// ---------------- pass B: pv[i,hd], rowsum[i] over a j-half ----------------
// grid (16 i-tiles, 2 j-splits, 16 bh), 256 thr; 64x64 tiles
__global__ __launch_bounds__(256) void pass_b(
    const float* __restrict__ q, const float* __restrict__ kbuf,
    const float* __restrict__ vbuf, const float* __restrict__ colsum,
    float* __restrict__ pv_base, float* __restrict__ rs_base)
{
    int bh = blockIdx.z;
    int i0 = blockIdx.x * 64;
    int split = blockIdx.y;
    int t = threadIdx.x;
    int tr = t >> 4, tc = t & 15;
    __shared__ alignas(16) float Qs[16][64];
    __shared__ alignas(16) float Ks[16][64];
    __shared__ alignas(16) float Vs[64][64];
    __shared__ alignas(16) float Ps[64][72];   // [j][i], +8 pad
    __shared__ float cs[64];
    const float* qb = q + (size_t)bh * NSINK * HD;
    const float* kb = kbuf + (size_t)bh * NSRC * HD;
    const float* vb = vbuf + (size_t)bh * NSRC * HD;
    float* pvp = pv_base + (size_t)split * BATCH * NSINK * DIM;
    float* rsp = rs_base + (size_t)split * BATCH * NH * NSINK;
    float acc2[4][4] = {};   // out [i=tr*4+r][d=tc*4+c]
    float rsum[4] = {};
    int jbeg = split * (NSRC / 2), jend = jbeg + (NSRC / 2);

    for (int j0 = jbeg; j0 < jend; j0 += 64) {
        if (t < 64) cs[t] = colsum[(size_t)bh * NSRC + j0 + t];
        float acc[4][4] = {};
        for (int kc = 0; kc < HD; kc += 16) {
            int row = t >> 2, seg = t & 3;
            float4 v = *(const float4*)&qb[(size_t)(i0 + row) * HD + kc + seg * 4];
            Qs[seg*4+0][row] = v.x; Qs[seg*4+1][row] = v.y;
            Qs[seg*4+2][row] = v.z; Qs[seg*4+3][row] = v.w;
            float4 w = *(const float4*)&kb[(size_t)(j0 + row) * HD + kc + seg * 4];
            Ks[seg*4+0][row] = w.x; Ks[seg*4+1][row] = w.y;
            Ks[seg*4+2][row] = w.z; Ks[seg*4+3][row] = w.w;
            __syncthreads();
            #pragma unroll
            for (int kk = 0; kk < 16; ++kk) {
                float4 af = *(const float4*)&Qs[kk][tr*4];
                float4 bf = *(const float4*)&Ks[kk][tc*4];
                float a_[4] = {af.x, af.y, af.z, af.w};
                float b_[4] = {bf.x, bf.y, bf.z, bf.w};
                #pragma unroll
                for (int r = 0; r < 4; ++r)
                    #pragma unroll
                    for (int c = 0; c < 4; ++c)
                        acc[r][c] += a_[r] * b_[c];
            }
            __syncthreads();
        }
        // p = exp2(sim') / colsum; write transposed Ps[j][i]; accumulate rowsum
        #pragma unroll
        for (int c = 0; c < 4; ++c) {
            float inv = 1.0f / cs[tc*4 + c];
            float p0 = fast_exp2(acc[0][c]) * inv;
            float p1 = fast_exp2(acc[1][c]) * inv;
            float p2 = fast_exp2(acc[2][c]) * inv;
            float p3 = fast_exp2(acc[3][c]) * inv;
            rsum[0] += p0; rsum[1] += p1; rsum[2] += p2; rsum[3] += p3;
            *(float4*)&Ps[tc*4 + c][tr*4] = make_float4(p0, p1, p2, p3);
        }
        #pragma unroll
        for (int l = 0; l < 4; ++l) {
            int fid = t + l * 256;
            int row = fid >> 4, col = (fid & 15) * 4;
            *(float4*)&Vs[row][col] = *(const float4*)&vb[(size_t)(j0 + row) * HD + col];
        }
        __syncthreads();
        #pragma unroll
        for (int jj = 0; jj < 64; ++jj) {
            float4 af = *(const float4*)&Ps[jj][tr*4];
            float4 bf = *(const float4*)&Vs[jj][tc*4];
            float a_[4] = {af.x, af.y, af.z, af.w};
            float b_[4] = {bf.x, bf.y, bf.z, bf.w};
            #pragma unroll
            for (int r = 0; r < 4; ++r)
                #pragma unroll
                for (int c = 0; c < 4; ++c)
                    acc2[r][c] += a_[r] * b_[c];
        }
        __syncthreads();
    }
    // rowsum reduce across tc
    float* red = &Ps[0][0];   // [64][16]
    #pragma unroll
    for (int r = 0; r < 4; ++r) red[(tr*4 + r) * 16 + tc] = rsum[r];
    __syncthreads();
    if (t < 64) {
        float s = 0.f;
        #pragma unroll
        for (int w = 0; w < 16; ++w) s += red[t * 16 + w];
        rsp[(size_t)bh * NSINK + i0 + t] = s;
    }
    int b = bh >> 3, h = bh & 7;
    #pragma unroll
    for (int r = 0; r < 4; ++r) {
        int i = i0 + tr*4 + r;
        #pragma unroll
        for (int c = 0; c < 4; ++c)
            pvp[((size_t)(b * NSINK + i)) * DIM + h * HD + tc*4 + c] = acc2[r][c];
    }
}

extern "C" void kernel_launch(void* const* d_in, const int* in_sizes, int n_in,
                              void* d_out, int out_size, void* d_ws, size_t ws_size,
                              hipStream_t stream) {
    (void)in_sizes; (void)n_in; (void)out_size;
    const float* sink    = (const float*)d_in[0];
    const float* source  = (const float*)d_in[1];
    const float* gamma_s = (const float*)d_in[2];
    const float* beta_s  = (const float*)d_in[3];
    const float* gamma_c = (const float*)d_in[4];
    const float* beta_c  = (const float*)d_in[5];
    const float* Wq      = (const float*)d_in[6];
    const float* bq      = (const float*)d_in[7];
    const float* Wkv     = (const float*)d_in[8];
    const float* bkv     = (const float*)d_in[9];
    const float* Wo      = (const float*)d_in[10];
    const float* bo      = (const float*)d_in[11];
    float* out = (float*)d_out;
    float* ws  = (float*)d_ws;

    float* s_n    = ws;                 // 2*1024*512   = 1,048,576
    float* c_n    = s_n + 1048576;      // 2*4096*512   = 4,194,304
    float* qb     = c_n + 4194304;      // 2*8*1024*64  = 1,048,576
    float* kb     = qb  + 1048576;      // 2*8*4096*64  = 4,194,304
    float* vb     = kb  + 4194304;      // 4,194,304
    float* colsum = vb  + 4194304;      // 65,536
    float* vsump  = colsum + 65536;     // 8,192
    float* vsumf  = vsump + 8192;       // 1,024
    float* pv     = vsumf + 1024;       // 2 * 1,048,576
    float* rs     = pv + 2097152;       // 2 * 16,384
    size_t need = (size_t)(16884736) * sizeof(float);
    if (ws_size < need) return;  // fail loudly (output stays poisoned)

    ln_kernel<<<BATCH * NSINK, 256, 0, stream>>>(sink, gamma_s, beta_s, s_n);
    ln_kernel<<<BATCH * NSRC,  256, 0, stream>>>(source, gamma_c, beta_c, c_n);

    gemm64<1><<<dim3(DIM / 64, BATCH * NSINK / 64), 256, 0, stream>>>(
        s_n, Wq, bq, qb, nullptr, BATCH * NSINK, DIM, DIM,
        nullptr, nullptr, nullptr, nullptr);
    gemm64<2><<<dim3(2 * DIM / 64, BATCH * NSRC / 64), 256, 0, stream>>>(
        c_n, Wkv, bkv, kb, vb, BATCH * NSRC, 2 * DIM, DIM,
        nullptr, nullptr, nullptr, nullptr);

    vsum_part<<<dim3(8, BATCH * NH), 256, 0, stream>>>(vb, vsump);
    vsum_fin<<<1, 1024, 0, stream>>>(vsump, vsumf);

    pass_a<<<dim3(NSRC / 128, BATCH * NH), 256, 0, stream>>>(qb, kb, colsum);
    pass_b<<<dim3(NSINK / 64, 2, BATCH * NH), 256, 0, stream>>>(
        qb, kb, vb, colsum, pv, rs);

    gemm64<3><<<dim3(DIM / 64, BATCH * NSINK / 64), 256, 0, stream>>>(
        pv, Wo, bo, out, nullptr, BATCH * NSINK, DIM, DIM,
        pv + 1048576, vsumf, rs, rs + 16384);
}

// Round 3
// 257.514 us; speedup vs baseline: 2.6055x; 2.6055x over previous
//
#include <hip/hip_runtime.h>
#include <hip/hip_bf16.h>
#include <math.h>

#define EPS 1e-6f
#define NSINK 1024
#define NSRC 4096
#define DIM 512
#define NH 8
#define HD 64
#define BATCH 2
// fold (d^-0.5 = 1/8) * log2(e) into q so sim exp is a single exp2
#define QSCALE 0.18033688011112042f

typedef unsigned short u16;
typedef __attribute__((ext_vector_type(8))) short short8;
typedef __attribute__((ext_vector_type(4))) float f32x4;

__device__ inline float fast_exp2(float x) {
#if __has_builtin(__builtin_amdgcn_exp2f)
    return __builtin_amdgcn_exp2f(x);
#else
    return exp2f(x);
#endif
}
__device__ inline float fast_rcp(float x) {
#if __has_builtin(__builtin_amdgcn_rcpf)
    return __builtin_amdgcn_rcpf(x);
#else
    return 1.0f / x;
#endif
}
__device__ inline u16 f2bf(float x) {
    union { float f; unsigned u; } v; v.f = x;
    unsigned r = v.u + 0x7fffu + ((v.u >> 16) & 1u);
    return (u16)(r >> 16);
}
__device__ inline float bf2f(u16 h) {
    union { unsigned u; float f; } v; v.u = ((unsigned)h) << 16;
    return v.f;
}
__device__ inline f32x4 mfma16(short8 a, short8 b, f32x4 c) {
    return __builtin_amdgcn_mfma_f32_16x16x32_bf16(a, b, c, 0, 0, 0);
}
// A-frag / BT-frag loader: row-major [*][stride] bf16, lane l -> row (l&15), cols (l>>4)*8..+8
__device__ inline short8 ldfrag(const u16* base, int stride, int lane) {
    return *(const short8*)(base + (size_t)(lane & 15) * stride + ((lane >> 4) << 3));
}

// ---------------- LayerNorm (row=512) -> split bf16 hi/lo ----------------
__global__ __launch_bounds__(256) void ln_split(const float* __restrict__ x,
    const float* __restrict__ g, const float* __restrict__ be,
    u16* __restrict__ yh, u16* __restrict__ yl)
{
    int row = blockIdx.x;
    int t = threadIdx.x;
    const float* xr = x + (size_t)row * DIM;
    float v0 = xr[t], v1 = xr[t + 256];
    float s = v0 + v1, sq = v0 * v0 + v1 * v1;
    #pragma unroll
    for (int off = 32; off > 0; off >>= 1) {
        s  += __shfl_down(s, off, 64);
        sq += __shfl_down(sq, off, 64);
    }
    __shared__ float rs[4], rq[4];
    int wave = t >> 6;
    if ((t & 63) == 0) { rs[wave] = s; rq[wave] = sq; }
    __syncthreads();
    s  = rs[0] + rs[1] + rs[2] + rs[3];
    sq = rq[0] + rq[1] + rq[2] + rq[3];
    float mu = s * (1.0f / DIM);
    float var = sq * (1.0f / DIM) - mu * mu;
    float a = var + EPS;
    float r = rsqrtf(a);
    r = r * (1.5f - 0.5f * a * r * r);
    size_t o = (size_t)row * DIM;
    float y0 = (v0 - mu) * r * g[t] + be[t];
    float y1 = (v1 - mu) * r * g[t + 256] + be[t + 256];
    u16 h0 = f2bf(y0), h1 = f2bf(y1);
    yh[o + t] = h0;        yl[o + t] = f2bf(y0 - bf2f(h0));
    yh[o + t + 256] = h1;  yl[o + t + 256] = f2bf(y1 - bf2f(h1));
}

// ---------------- weight transpose + split: W[K][N] -> T{h,l}[N][K] ----------------
__global__ __launch_bounds__(256) void wt_split(const float* __restrict__ W, int K, int N,
    u16* __restrict__ Th, u16* __restrict__ Tl)
{
    int n = blockIdx.x;
    for (int k = threadIdx.x; k < K; k += 256) {
        float w = W[(size_t)k * N + n];
        u16 h = f2bf(w);
        Th[(size_t)n * K + k] = h;
        Tl[(size_t)n * K + k] = f2bf(w - bf2f(h));
    }
}

// ---------------- split-3 MFMA GEMM: C[64x64 tile] = A @ BT^T + bias ----------------
// MODE 0: C fp32 row-major (d_out).  MODE 1: q bf16 [bh][i][d] * QSCALE.
// MODE 2: n<512 -> k bf16 [bh][j][d]; n>=512 -> vT split [bh*64+d][j].
template<int MODE>
__global__ __launch_bounds__(256) void gemm_s3(
    const u16* __restrict__ Ah, const u16* __restrict__ Al,
    const u16* __restrict__ BTh, const u16* __restrict__ BTl,
    const float* __restrict__ bias, int K,
    float* __restrict__ cf, u16* __restrict__ o1,
    u16* __restrict__ o2, u16* __restrict__ o3)
{
    int wave = threadIdx.x >> 6, lane = threadIdx.x & 63;
    int m0 = blockIdx.y * 64, n0 = blockIdx.x * 64;
    f32x4 acc[4][4] = {};
    int kpw = K >> 7;   // k-chunks (32) per wave, 4-way K-split
    for (int kc = 0; kc < kpw; ++kc) {
        int k0 = (wave * kpw + kc) << 5;
        short8 ah[4], al[4], bh[4], bl[4];
        #pragma unroll
        for (int f = 0; f < 4; ++f) {
            ah[f] = ldfrag(Ah + (size_t)(m0 + f * 16) * K + k0, K, lane);
            al[f] = ldfrag(Al + (size_t)(m0 + f * 16) * K + k0, K, lane);
            bh[f] = ldfrag(BTh + (size_t)(n0 + f * 16) * K + k0, K, lane);
            bl[f] = ldfrag(BTl + (size_t)(n0 + f * 16) * K + k0, K, lane);
        }
        #pragma unroll
        for (int i = 0; i < 4; ++i)
            #pragma unroll
            for (int j = 0; j < 4; ++j) {
                acc[i][j] = mfma16(al[i], bh[j], acc[i][j]);
                acc[i][j] = mfma16(ah[i], bl[j], acc[i][j]);
                acc[i][j] = mfma16(ah[i], bh[j], acc[i][j]);
            }
    }
    __shared__ alignas(16) float red[64][68];
    for (int w = 0; w < 4; ++w) {
        if (wave == w) {
            #pragma unroll
            for (int i = 0; i < 4; ++i)
                #pragma unroll
                for (int j = 0; j < 4; ++j)
                    #pragma unroll
                    for (int r = 0; r < 4; ++r) {
                        int row = i * 16 + (lane >> 4) * 4 + r;
                        int col = j * 16 + (lane & 15);
                        if (w == 0) red[row][col] = acc[i][j][r];
                        else        red[row][col] += acc[i][j][r];
                    }
        }
        __syncthreads();
    }
    int i = threadIdx.x >> 2, jb = (threadIdx.x & 3) * 16;
    int m = m0 + i;
    #pragma unroll
    for (int jj = 0; jj < 16; ++jj) {
        int n = n0 + jb + jj;
        float v = red[i][jb + jj] + bias[n];
        if (MODE == 0) {
            cf[(size_t)m * DIM + n] = v;
        } else if (MODE == 1) {
            int b = m >> 10, ii = m & 1023;
            int h = n >> 6, d = n & 63;
            o1[((size_t)(b * NH + h) * NSINK + ii) * HD + d] = f2bf(v * QSCALE);
        } else {
            int b = m >> 12, j = m & 4095;
            if (n < DIM) {
                int h = n >> 6, d = n & 63;
                o1[((size_t)(b * NH + h) * NSRC + j) * HD + d] = f2bf(v);
            } else {
                int nn = n - DIM;
                int h = nn >> 6, d = nn & 63;
                size_t off = ((size_t)(b * NH + h) * HD + d) * NSRC + j;
                u16 hh = f2bf(v);
                o2[off] = hh;
                o3[off] = f2bf(v - bf2f(hh));
            }
        }
    }
}

// ---------------- vsum[bh*64+d] = sum_j v ----------------
__global__ __launch_bounds__(256) void vsum_k(const u16* __restrict__ vTh,
    const u16* __restrict__ vTl, float* __restrict__ vs)
{
    int row = blockIdx.x;
    const u16* ph = vTh + (size_t)row * NSRC;
    const u16* pl = vTl + (size_t)row * NSRC;
    float s = 0.f;
    for (int j = threadIdx.x; j < NSRC; j += 256) s += bf2f(ph[j]) + bf2f(pl[j]);
    #pragma unroll
    for (int off = 32; off > 0; off >>= 1) s += __shfl_down(s, off, 64);
    __shared__ float r4[4];
    if ((threadIdx.x & 63) == 0) r4[threadIdx.x >> 6] = s;
    __syncthreads();
    if (threadIdx.x == 0) vs[row] = r4[0] + r4[1] + r4[2] + r4[3];
}

// ---------------- pass A: colsum[bh][j] = sum_i exp2(q.k) ----------------
__global__ __launch_bounds__(256, 2) void pass_a(const u16* __restrict__ q,
    const u16* __restrict__ k, float* __restrict__ colsum)
{
    int bh = blockIdx.y;
    int wave = threadIdx.x >> 6, lane = threadIdx.x & 63;
    int j0 = blockIdx.x * 256 + wave * 64;
    const u16* qb = q + (size_t)bh * NSINK * HD;
    const u16* kb = k + (size_t)bh * NSRC * HD;
    short8 kf[4][2];
    #pragma unroll
    for (int jf = 0; jf < 4; ++jf)
        #pragma unroll
        for (int kc = 0; kc < 2; ++kc)
            kf[jf][kc] = ldfrag(kb + (size_t)(j0 + jf * 16) * HD + kc * 32, HD, lane);
    float csum[4] = {};
    for (int i0 = 0; i0 < NSINK; i0 += 64) {
        short8 qf[4][2];
        #pragma unroll
        for (int f = 0; f < 4; ++f)
            #pragma unroll
            for (int kc = 0; kc < 2; ++kc)
                qf[f][kc] = ldfrag(qb + (size_t)(i0 + f * 16) * HD + kc * 32, HD, lane);
        f32x4 acc[4][4] = {};
        #pragma unroll
        for (int kc = 0; kc < 2; ++kc)
            #pragma unroll
            for (int i = 0; i < 4; ++i)
                #pragma unroll
                for (int j = 0; j < 4; ++j)
                    acc[i][j] = mfma16(qf[i][kc], kf[j][kc], acc[i][j]);
        #pragma unroll
        for (int i = 0; i < 4; ++i)
            #pragma unroll
            for (int j = 0; j < 4; ++j)
                csum[j] += fast_exp2(acc[i][j][0]) + fast_exp2(acc[i][j][1])
                         + fast_exp2(acc[i][j][2]) + fast_exp2(acc[i][j][3]);
    }
    #pragma unroll
    for (int j = 0; j < 4; ++j) {
        csum[j] += __shfl_xor(csum[j], 16, 64);
        csum[j] += __shfl_xor(csum[j], 32, 64);
    }
    if (lane < 16)
        #pragma unroll
        for (int j = 0; j < 4; ++j)
            colsum[(size_t)bh * NSRC + j0 + j * 16 + lane] = csum[j];
}

// ---------------- pass B: pv[i][hd], rowsum[i] per j-half ----------------
__global__ __launch_bounds__(256, 2) void pass_b(const u16* __restrict__ q,
    const u16* __restrict__ k, const u16* __restrict__ vTh, const u16* __restrict__ vTl,
    const float* __restrict__ colsum, float* __restrict__ pv, float* __restrict__ rs)
{
    int bh = blockIdx.z, i0 = blockIdx.x * 64, split = blockIdx.y;
    int wave = threadIdx.x >> 6, lane = threadIdx.x & 63;
    const u16* qb = q + (size_t)bh * NSINK * HD;
    const u16* kb = k + (size_t)bh * NSRC * HD;
    const u16* vh = vTh + (size_t)bh * HD * NSRC;
    const u16* vl = vTl + (size_t)bh * HD * NSRC;
    __shared__ alignas(16) u16 pbuf[4][64 * 72];
    __shared__ float rsums[4][64];
    short8 qf[4][2];
    #pragma unroll
    for (int f = 0; f < 4; ++f)
        #pragma unroll
        for (int kc = 0; kc < 2; ++kc)
            qf[f][kc] = ldfrag(qb + (size_t)(i0 + f * 16) * HD + kc * 32, HD, lane);
    f32x4 o[4][4] = {};
    float rsum[4][4] = {};
    for (int jt = 0; jt < 8; ++jt) {
        int j0 = split * (NSRC / 2) + jt * 256 + wave * 64;
        short8 kf[4][2];
        #pragma unroll
        for (int jf = 0; jf < 4; ++jf)
            #pragma unroll
            for (int kc = 0; kc < 2; ++kc)
                kf[jf][kc] = ldfrag(kb + (size_t)(j0 + jf * 16) * HD + kc * 32, HD, lane);
        float inv[4];
        #pragma unroll
        for (int jf = 0; jf < 4; ++jf)
            inv[jf] = fast_rcp(colsum[(size_t)bh * NSRC + j0 + jf * 16 + (lane & 15)]);
        #pragma unroll
        for (int i = 0; i < 4; ++i) {
            f32x4 s[4] = {};
            #pragma unroll
            for (int kc = 0; kc < 2; ++kc)
                #pragma unroll
                for (int jf = 0; jf < 4; ++jf)
                    s[jf] = mfma16(qf[i][kc], kf[jf][kc], s[jf]);
            #pragma unroll
            for (int jf = 0; jf < 4; ++jf) {
                float p0 = fast_exp2(s[jf][0]) * inv[jf];
                float p1 = fast_exp2(s[jf][1]) * inv[jf];
                float p2 = fast_exp2(s[jf][2]) * inv[jf];
                float p3 = fast_exp2(s[jf][3]) * inv[jf];
                rsum[i][0] += p0; rsum[i][1] += p1; rsum[i][2] += p2; rsum[i][3] += p3;
                u16* dst = &pbuf[wave][(size_t)(i * 16 + (lane >> 4) * 4) * 72 + jf * 16 + (lane & 15)];
                dst[0]      = f2bf(p0);
                dst[72]     = f2bf(p1);
                dst[2 * 72] = f2bf(p2);
                dst[3 * 72] = f2bf(p3);
            }
        }
        __syncthreads();
        #pragma unroll
        for (int jc = 0; jc < 2; ++jc) {
            short8 pa[4];
            #pragma unroll
            for (int f = 0; f < 4; ++f)
                pa[f] = *(const short8*)&pbuf[wave][(size_t)(f * 16 + (lane & 15)) * 72 + jc * 32 + (lane >> 4) * 8];
            #pragma unroll
            for (int df = 0; df < 4; ++df) {
                short8 bhf = ldfrag(vh + (size_t)(df * 16) * NSRC + j0 + jc * 32, NSRC, lane);
                short8 blf = ldfrag(vl + (size_t)(df * 16) * NSRC + j0 + jc * 32, NSRC, lane);
                #pragma unroll
                for (int i = 0; i < 4; ++i) {
                    o[i][df] = mfma16(pa[i], bhf, o[i][df]);
                    o[i][df] = mfma16(pa[i], blf, o[i][df]);
                }
            }
        }
        __syncthreads();
    }
    // ---- rowsum: reduce within wave (across the 16 key-columns) ----
    #pragma unroll
    for (int i = 0; i < 4; ++i)
        #pragma unroll
        for (int r = 0; r < 4; ++r) {
            float v = rsum[i][r];
            v += __shfl_xor(v, 1, 64); v += __shfl_xor(v, 2, 64);
            v += __shfl_xor(v, 4, 64); v += __shfl_xor(v, 8, 64);
            if ((lane & 15) == 0) rsums[wave][i * 16 + (lane >> 4) * 4 + r] = v;
        }
    // ---- cross-wave reduction of o (each wave holds a disjoint key-quarter!)
    // Reuse pbuf as float[64][68] scratch (17408 B <= 36864 B). Last loop
    // iteration ended with __syncthreads(), so pbuf reads are complete.
    float* redo = (float*)&pbuf[0][0];
    for (int w = 0; w < 4; ++w) {
        if (wave == w) {
            #pragma unroll
            for (int i = 0; i < 4; ++i)
                #pragma unroll
                for (int df = 0; df < 4; ++df)
                    #pragma unroll
                    for (int r = 0; r < 4; ++r) {
                        int row = i * 16 + (lane >> 4) * 4 + r;
                        int col = df * 16 + (lane & 15);
                        if (w == 0) redo[row * 68 + col] = o[i][df][r];
                        else        redo[row * 68 + col] += o[i][df][r];
                    }
        }
        __syncthreads();
    }
    if (threadIdx.x < 64) {
        float v = rsums[0][threadIdx.x] + rsums[1][threadIdx.x]
                + rsums[2][threadIdx.x] + rsums[3][threadIdx.x];
        rs[((size_t)split * (BATCH * NH) + bh) * NSINK + i0 + threadIdx.x] = v;
    }
    int b = bh >> 3, h = bh & 7;
    float* pvp = pv + (size_t)split * BATCH * NSINK * DIM;
    {
        int row = threadIdx.x >> 2, cb = (threadIdx.x & 3) * 16;
        float* dst = &pvp[((size_t)(b * NSINK + i0 + row)) * DIM + h * HD + cb];
        #pragma unroll
        for (int jj = 0; jj < 16; ++jj) dst[jj] = redo[row * 68 + cb + jj];
    }
}

// ---------------- finalize: a = (pv0+pv1+eps*vsum)/(rs0+rs1+Neps) -> split bf16 ----------------
__global__ __launch_bounds__(256) void finalize_pv(const float* __restrict__ pv,
    const float* __restrict__ rs, const float* __restrict__ vs,
    u16* __restrict__ ah, u16* __restrict__ al)
{
    int idx = blockIdx.x * 256 + threadIdx.x;
    int m = idx >> 9, n = idx & 511;
    int b = m >> 10, i = m & 1023, h = n >> 6, d = n & 63;
    int bh = b * NH + h;
    float val = pv[idx] + pv[idx + BATCH * NSINK * DIM] + EPS * vs[bh * HD + d];
    val /= (rs[bh * NSINK + i] + rs[BATCH * NH * NSINK + bh * NSINK + i] + (float)NSRC * EPS);
    u16 hh = f2bf(val);
    ah[idx] = hh;
    al[idx] = f2bf(val - bf2f(hh));
}

extern "C" void kernel_launch(void* const* d_in, const int* in_sizes, int n_in,
                              void* d_out, int out_size, void* d_ws, size_t ws_size,
                              hipStream_t stream) {
    (void)in_sizes; (void)n_in; (void)out_size;
    const float* sink    = (const float*)d_in[0];
    const float* source  = (const float*)d_in[1];
    const float* gamma_s = (const float*)d_in[2];
    const float* beta_s  = (const float*)d_in[3];
    const float* gamma_c = (const float*)d_in[4];
    const float* beta_c  = (const float*)d_in[5];
    const float* Wq      = (const float*)d_in[6];
    const float* bq      = (const float*)d_in[7];
    const float* Wkv     = (const float*)d_in[8];
    const float* bkv     = (const float*)d_in[9];
    const float* Wo      = (const float*)d_in[10];
    const float* bo      = (const float*)d_in[11];
    float* out = (float*)d_out;

    char* p = (char*)d_ws;
    auto carve = [&](size_t bytes) { char* r = p; p += (bytes + 255) & ~(size_t)255; return r; };
    u16* sh    = (u16*)carve(2048ull * 512 * 2);
    u16* sl    = (u16*)carve(2048ull * 512 * 2);
    u16* ch    = (u16*)carve(8192ull * 512 * 2);
    u16* cl    = (u16*)carve(8192ull * 512 * 2);
    u16* wqTh  = (u16*)carve(512ull * 512 * 2);
    u16* wqTl  = (u16*)carve(512ull * 512 * 2);
    u16* wkvTh = (u16*)carve(1024ull * 512 * 2);
    u16* wkvTl = (u16*)carve(1024ull * 512 * 2);
    u16* woTh  = (u16*)carve(512ull * 512 * 2);
    u16* woTl  = (u16*)carve(512ull * 512 * 2);
    u16* qb    = (u16*)carve(16ull * 1024 * 64 * 2);
    u16* kb    = (u16*)carve(16ull * 4096 * 64 * 2);
    u16* vTh   = (u16*)carve(16ull * 64 * 4096 * 2);
    u16* vTl   = (u16*)carve(16ull * 64 * 4096 * 2);
    float* colsum = (float*)carve(16ull * 4096 * 4);
    float* vs     = (float*)carve(1024ull * 4);
    float* pv     = (float*)carve(2ull * 2048 * 512 * 4);
    float* rs     = (float*)carve(2ull * 16 * 1024 * 4);
    u16* ah    = (u16*)carve(2048ull * 512 * 2);
    u16* al    = (u16*)carve(2048ull * 512 * 2);
    if ((size_t)(p - (char*)d_ws) > ws_size) return;

    ln_split<<<BATCH * NSINK, 256, 0, stream>>>(sink, gamma_s, beta_s, sh, sl);
    ln_split<<<BATCH * NSRC,  256, 0, stream>>>(source, gamma_c, beta_c, ch, cl);
    wt_split<<<512,  256, 0, stream>>>(Wq, 512, 512, wqTh, wqTl);
    wt_split<<<1024, 256, 0, stream>>>(Wkv, 512, 1024, wkvTh, wkvTl);
    wt_split<<<512,  256, 0, stream>>>(Wo, 512, 512, woTh, woTl);

    gemm_s3<1><<<dim3(8, 32), 256, 0, stream>>>(sh, sl, wqTh, wqTl, bq, 512,
        nullptr, qb, nullptr, nullptr);
    gemm_s3<2><<<dim3(16, 128), 256, 0, stream>>>(ch, cl, wkvTh, wkvTl, bkv, 512,
        nullptr, kb, vTh, vTl);

    vsum_k<<<1024, 256, 0, stream>>>(vTh, vTl, vs);
    pass_a<<<dim3(16, 16), 256, 0, stream>>>(qb, kb, colsum);
    pass_b<<<dim3(16, 2, 16), 256, 0, stream>>>(qb, kb, vTh, vTl, colsum, pv, rs);
    finalize_pv<<<4096, 256, 0, stream>>>(pv, rs, vs, ah, al);

    gemm_s3<0><<<dim3(8, 32), 256, 0, stream>>>(ah, al, woTh, woTl, bo, 512,
        out, nullptr, nullptr, nullptr);
}

// Round 4
// 226.130 us; speedup vs baseline: 2.9672x; 1.1388x over previous
//
#include <hip/hip_runtime.h>
#include <hip/hip_bf16.h>
#include <math.h>

#define EPS 1e-6f
#define NSINK 1024
#define NSRC 4096
#define DIM 512
#define NH 8
#define HD 64
#define BATCH 2
// fold (d^-0.5 = 1/8) * log2(e) into q so sim exp is a single exp2
#define QSCALE 0.18033688011112042f

typedef unsigned short u16;
typedef __attribute__((ext_vector_type(8))) short short8;
typedef __attribute__((ext_vector_type(4))) float f32x4;

__device__ inline float fast_exp2(float x) {
#if __has_builtin(__builtin_amdgcn_exp2f)
    return __builtin_amdgcn_exp2f(x);
#else
    return exp2f(x);
#endif
}
__device__ inline float fast_rcp(float x) {
#if __has_builtin(__builtin_amdgcn_rcpf)
    return __builtin_amdgcn_rcpf(x);
#else
    return 1.0f / x;
#endif
}
__device__ inline u16 f2bf(float x) {
    union { float f; unsigned u; } v; v.f = x;
    unsigned r = v.u + 0x7fffu + ((v.u >> 16) & 1u);
    return (u16)(r >> 16);
}
__device__ inline float bf2f(u16 h) {
    union { unsigned u; float f; } v; v.u = ((unsigned)h) << 16;
    return v.f;
}
__device__ inline f32x4 mfma16(short8 a, short8 b, f32x4 c) {
    return __builtin_amdgcn_mfma_f32_16x16x32_bf16(a, b, c, 0, 0, 0);
}
// direct-from-global fragment loader (used by pass_a / pass_b)
__device__ inline short8 ldfrag(const u16* base, int stride, int lane) {
    return *(const short8*)(base + (size_t)(lane & 15) * stride + ((lane >> 4) << 3));
}

// async global->LDS, 16B per lane
__device__ inline void gld16(const u16* g, u16* l) {
    __builtin_amdgcn_global_load_lds(
        (const __attribute__((address_space(1))) unsigned*)g,
        (__attribute__((address_space(3))) unsigned*)l, 16, 0, 0);
}

// stage a [TM][64] bf16 tile (row-major, 128B rows) from gsrc (row-major, stride K)
// LDS is linear (thread t -> byte t*16 per iteration); global source is
// INVERSE-swizzled (c ^= m&7) so that swizzled ds_reads are conflict-free.
template<int TM>
__device__ inline void stage_tile(u16* lds, const u16* gsrc, int K, int t) {
    #pragma unroll
    for (int it = 0; it < TM / 32; ++it) {
        int m = it * 32 + (t >> 3);
        int c = (t & 7) ^ (m & 7);
        gld16(gsrc + (size_t)m * K + c * 8,
              lds + it * 2048 + (t >> 6) * 512);
    }
}
// swizzled fragment read: rows fbase..fbase+16, k-cols cbase*8..(+8 per l>>4)
__device__ inline short8 rdfrag(const u16* tile, int fbase, int cbase, int lane) {
    int m = fbase + (lane & 15);
    int c = (cbase + (lane >> 4)) ^ (m & 7);
    return *(const short8*)(tile + (size_t)m * 64 + c * 8);
}

// ---------------- LayerNorm (row=512) -> split bf16 hi/lo ----------------
__global__ __launch_bounds__(256) void ln_split(const float* __restrict__ x,
    const float* __restrict__ g, const float* __restrict__ be,
    u16* __restrict__ yh, u16* __restrict__ yl)
{
    int row = blockIdx.x;
    int t = threadIdx.x;
    const float* xr = x + (size_t)row * DIM;
    float v0 = xr[t], v1 = xr[t + 256];
    float s = v0 + v1, sq = v0 * v0 + v1 * v1;
    #pragma unroll
    for (int off = 32; off > 0; off >>= 1) {
        s  += __shfl_down(s, off, 64);
        sq += __shfl_down(sq, off, 64);
    }
    __shared__ float rs[4], rq[4];
    int wave = t >> 6;
    if ((t & 63) == 0) { rs[wave] = s; rq[wave] = sq; }
    __syncthreads();
    s  = rs[0] + rs[1] + rs[2] + rs[3];
    sq = rq[0] + rq[1] + rq[2] + rq[3];
    float mu = s * (1.0f / DIM);
    float var = sq * (1.0f / DIM) - mu * mu;
    float a = var + EPS;
    float r = rsqrtf(a);
    r = r * (1.5f - 0.5f * a * r * r);
    size_t o = (size_t)row * DIM;
    float y0 = (v0 - mu) * r * g[t] + be[t];
    float y1 = (v1 - mu) * r * g[t + 256] + be[t + 256];
    u16 h0 = f2bf(y0), h1 = f2bf(y1);
    yh[o + t] = h0;        yl[o + t] = f2bf(y0 - bf2f(h0));
    yh[o + t + 256] = h1;  yl[o + t + 256] = f2bf(y1 - bf2f(h1));
}

// ---------------- weight transpose + split: W[K][N] -> T{h,l}[N][K] ----------------
__global__ __launch_bounds__(256) void wt_split(const float* __restrict__ W, int K, int N,
    u16* __restrict__ Th, u16* __restrict__ Tl)
{
    int n = blockIdx.x;
    for (int k = threadIdx.x; k < K; k += 256) {
        float w = W[(size_t)k * N + n];
        u16 h = f2bf(w);
        Th[(size_t)n * K + k] = h;
        Tl[(size_t)n * K + k] = f2bf(w - bf2f(h));
    }
}

// ---------------- LDS-staged MFMA GEMM: C = A @ BT^T + bias ----------------
// MODE 0: 3-term, C fp32 row-major (d_out).
// MODE 1: 1-term, q bf16 [bh][i][d] * QSCALE.
// MODE 2: n<512 -> 1-term, k bf16 [bh][j][d];  n>=512 -> 3-term, vT split [bh*64+d][j].
// 4 waves in 2x2, each owns a (TM/2)x(TN/2) quadrant; BK=64; no K-split.
template<int MODE, int TM, int TN>
__global__ __launch_bounds__(256) void gemm_lds(
    const u16* __restrict__ Ah, const u16* __restrict__ Al,
    const u16* __restrict__ BTh, const u16* __restrict__ BTl,
    const float* __restrict__ bias, int K,
    float* __restrict__ cf, u16* __restrict__ o1,
    u16* __restrict__ o2, u16* __restrict__ o3)
{
    constexpr int NSPLIT = (MODE == 1) ? 1 : 2;
    constexpr int FM = TM / 32, FN = TN / 32;
    __shared__ u16 As[NSPLIT][TM * 64];
    __shared__ u16 Bs[NSPLIT][TN * 64];
    int t = threadIdx.x;
    int wave = t >> 6, lane = t & 63;
    int wr = wave >> 1, wc = wave & 1;
    int m0 = blockIdx.y * TM, n0 = blockIdx.x * TN;
    bool three = (MODE == 0) || (MODE == 2 && n0 >= DIM);

    f32x4 acc[FM][FN] = {};
    for (int k0 = 0; k0 < K; k0 += 64) {
        stage_tile<TM>(&As[0][0], Ah + (size_t)m0 * K + k0, K, t);
        stage_tile<TN>(&Bs[0][0], BTh + (size_t)n0 * K + k0, K, t);
        if constexpr (MODE != 1) {
            if (three) {
                stage_tile<TM>(&As[1][0], Al + (size_t)m0 * K + k0, K, t);
                stage_tile<TN>(&Bs[1][0], BTl + (size_t)n0 * K + k0, K, t);
            }
        }
        __syncthreads();
        #pragma unroll
        for (int kk = 0; kk < 2; ++kk) {
            short8 afh[FM], bfh[FN];
            #pragma unroll
            for (int f = 0; f < FM; ++f)
                afh[f] = rdfrag(&As[0][0], wr * (TM / 2) + f * 16, kk * 4, lane);
            #pragma unroll
            for (int f = 0; f < FN; ++f)
                bfh[f] = rdfrag(&Bs[0][0], wc * (TN / 2) + f * 16, kk * 4, lane);
            if constexpr (MODE != 1) {
                if (three) {
                    short8 afl[FM], bfl[FN];
                    #pragma unroll
                    for (int f = 0; f < FM; ++f)
                        afl[f] = rdfrag(&As[1][0], wr * (TM / 2) + f * 16, kk * 4, lane);
                    #pragma unroll
                    for (int f = 0; f < FN; ++f)
                        bfl[f] = rdfrag(&Bs[1][0], wc * (TN / 2) + f * 16, kk * 4, lane);
                    #pragma unroll
                    for (int i = 0; i < FM; ++i)
                        #pragma unroll
                        for (int j = 0; j < FN; ++j) {
                            acc[i][j] = mfma16(afl[i], bfh[j], acc[i][j]);
                            acc[i][j] = mfma16(afh[i], bfl[j], acc[i][j]);
                            acc[i][j] = mfma16(afh[i], bfh[j], acc[i][j]);
                        }
                } else {
                    #pragma unroll
                    for (int i = 0; i < FM; ++i)
                        #pragma unroll
                        for (int j = 0; j < FN; ++j)
                            acc[i][j] = mfma16(afh[i], bfh[j], acc[i][j]);
                }
            } else {
                #pragma unroll
                for (int i = 0; i < FM; ++i)
                    #pragma unroll
                    for (int j = 0; j < FN; ++j)
                        acc[i][j] = mfma16(afh[i], bfh[j], acc[i][j]);
            }
        }
        __syncthreads();
    }

    #pragma unroll
    for (int i = 0; i < FM; ++i)
        #pragma unroll
        for (int j = 0; j < FN; ++j)
            #pragma unroll
            for (int r = 0; r < 4; ++r) {
                int m = m0 + wr * (TM / 2) + i * 16 + (lane >> 4) * 4 + r;
                int n = n0 + wc * (TN / 2) + j * 16 + (lane & 15);
                float v = acc[i][j][r] + bias[n];
                if (MODE == 0) {
                    cf[(size_t)m * DIM + n] = v;
                } else if (MODE == 1) {
                    int b = m >> 10, ii = m & 1023;
                    int h = n >> 6, d = n & 63;
                    o1[((size_t)(b * NH + h) * NSINK + ii) * HD + d] = f2bf(v * QSCALE);
                } else {
                    int b = m >> 12, jj = m & 4095;
                    if (n < DIM) {
                        int h = n >> 6, d = n & 63;
                        o1[((size_t)(b * NH + h) * NSRC + jj) * HD + d] = f2bf(v);
                    } else {
                        int nn = n - DIM;
                        int h = nn >> 6, d = nn & 63;
                        size_t off = ((size_t)(b * NH + h) * HD + d) * NSRC + jj;
                        u16 hh = f2bf(v);
                        o2[off] = hh;
                        o3[off] = f2bf(v - bf2f(hh));
                    }
                }
            }
}

// ---------------- vsum[bh*64+d] = sum_j v ----------------
__global__ __launch_bounds__(256) void vsum_k(const u16* __restrict__ vTh,
    const u16* __restrict__ vTl, float* __restrict__ vs)
{
    int row = blockIdx.x;
    const u16* ph = vTh + (size_t)row * NSRC;
    const u16* pl = vTl + (size_t)row * NSRC;
    float s = 0.f;
    for (int j = threadIdx.x; j < NSRC; j += 256) s += bf2f(ph[j]) + bf2f(pl[j]);
    #pragma unroll
    for (int off = 32; off > 0; off >>= 1) s += __shfl_down(s, off, 64);
    __shared__ float r4[4];
    if ((threadIdx.x & 63) == 0) r4[threadIdx.x >> 6] = s;
    __syncthreads();
    if (threadIdx.x == 0) vs[row] = r4[0] + r4[1] + r4[2] + r4[3];
}

// ---------------- pass A: colsum[bh][j] = sum_i exp2(q.k) ----------------
__global__ __launch_bounds__(256, 2) void pass_a(const u16* __restrict__ q,
    const u16* __restrict__ k, float* __restrict__ colsum)
{
    int bh = blockIdx.y;
    int wave = threadIdx.x >> 6, lane = threadIdx.x & 63;
    int j0 = blockIdx.x * 256 + wave * 64;
    const u16* qb = q + (size_t)bh * NSINK * HD;
    const u16* kb = k + (size_t)bh * NSRC * HD;
    short8 kf[4][2];
    #pragma unroll
    for (int jf = 0; jf < 4; ++jf)
        #pragma unroll
        for (int kc = 0; kc < 2; ++kc)
            kf[jf][kc] = ldfrag(kb + (size_t)(j0 + jf * 16) * HD + kc * 32, HD, lane);
    float csum[4] = {};
    for (int i0 = 0; i0 < NSINK; i0 += 64) {
        short8 qf[4][2];
        #pragma unroll
        for (int f = 0; f < 4; ++f)
            #pragma unroll
            for (int kc = 0; kc < 2; ++kc)
                qf[f][kc] = ldfrag(qb + (size_t)(i0 + f * 16) * HD + kc * 32, HD, lane);
        f32x4 acc[4][4] = {};
        #pragma unroll
        for (int kc = 0; kc < 2; ++kc)
            #pragma unroll
            for (int i = 0; i < 4; ++i)
                #pragma unroll
                for (int j = 0; j < 4; ++j)
                    acc[i][j] = mfma16(qf[i][kc], kf[j][kc], acc[i][j]);
        #pragma unroll
        for (int i = 0; i < 4; ++i)
            #pragma unroll
            for (int j = 0; j < 4; ++j)
                csum[j] += fast_exp2(acc[i][j][0]) + fast_exp2(acc[i][j][1])
                         + fast_exp2(acc[i][j][2]) + fast_exp2(acc[i][j][3]);
    }
    #pragma unroll
    for (int j = 0; j < 4; ++j) {
        csum[j] += __shfl_xor(csum[j], 16, 64);
        csum[j] += __shfl_xor(csum[j], 32, 64);
    }
    if (lane < 16)
        #pragma unroll
        for (int j = 0; j < 4; ++j)
            colsum[(size_t)bh * NSRC + j0 + j * 16 + lane] = csum[j];
}

// ---------------- pass B: pv[i][hd], rowsum[i] per j-half ----------------
__global__ __launch_bounds__(256, 2) void pass_b(const u16* __restrict__ q,
    const u16* __restrict__ k, const u16* __restrict__ vTh, const u16* __restrict__ vTl,
    const float* __restrict__ colsum, float* __restrict__ pv, float* __restrict__ rs)
{
    int bh = blockIdx.z, i0 = blockIdx.x * 64, split = blockIdx.y;
    int wave = threadIdx.x >> 6, lane = threadIdx.x & 63;
    const u16* qb = q + (size_t)bh * NSINK * HD;
    const u16* kb = k + (size_t)bh * NSRC * HD;
    const u16* vh = vTh + (size_t)bh * HD * NSRC;
    const u16* vl = vTl + (size_t)bh * HD * NSRC;
    __shared__ alignas(16) u16 pbuf[4][64 * 72];
    __shared__ float rsums[4][64];
    short8 qf[4][2];
    #pragma unroll
    for (int f = 0; f < 4; ++f)
        #pragma unroll
        for (int kc = 0; kc < 2; ++kc)
            qf[f][kc] = ldfrag(qb + (size_t)(i0 + f * 16) * HD + kc * 32, HD, lane);
    f32x4 o[4][4] = {};
    float rsum[4][4] = {};
    for (int jt = 0; jt < 8; ++jt) {
        int j0 = split * (NSRC / 2) + jt * 256 + wave * 64;
        short8 kf[4][2];
        #pragma unroll
        for (int jf = 0; jf < 4; ++jf)
            #pragma unroll
            for (int kc = 0; kc < 2; ++kc)
                kf[jf][kc] = ldfrag(kb + (size_t)(j0 + jf * 16) * HD + kc * 32, HD, lane);
        float inv[4];
        #pragma unroll
        for (int jf = 0; jf < 4; ++jf)
            inv[jf] = fast_rcp(colsum[(size_t)bh * NSRC + j0 + jf * 16 + (lane & 15)]);
        #pragma unroll
        for (int i = 0; i < 4; ++i) {
            f32x4 s[4] = {};
            #pragma unroll
            for (int kc = 0; kc < 2; ++kc)
                #pragma unroll
                for (int jf = 0; jf < 4; ++jf)
                    s[jf] = mfma16(qf[i][kc], kf[jf][kc], s[jf]);
            #pragma unroll
            for (int jf = 0; jf < 4; ++jf) {
                float p0 = fast_exp2(s[jf][0]) * inv[jf];
                float p1 = fast_exp2(s[jf][1]) * inv[jf];
                float p2 = fast_exp2(s[jf][2]) * inv[jf];
                float p3 = fast_exp2(s[jf][3]) * inv[jf];
                rsum[i][0] += p0; rsum[i][1] += p1; rsum[i][2] += p2; rsum[i][3] += p3;
                u16* dst = &pbuf[wave][(size_t)(i * 16 + (lane >> 4) * 4) * 72 + jf * 16 + (lane & 15)];
                dst[0]      = f2bf(p0);
                dst[72]     = f2bf(p1);
                dst[2 * 72] = f2bf(p2);
                dst[3 * 72] = f2bf(p3);
            }
        }
        __syncthreads();
        #pragma unroll
        for (int jc = 0; jc < 2; ++jc) {
            short8 pa[4];
            #pragma unroll
            for (int f = 0; f < 4; ++f)
                pa[f] = *(const short8*)&pbuf[wave][(size_t)(f * 16 + (lane & 15)) * 72 + jc * 32 + (lane >> 4) * 8];
            #pragma unroll
            for (int df = 0; df < 4; ++df) {
                short8 bhf = ldfrag(vh + (size_t)(df * 16) * NSRC + j0 + jc * 32, NSRC, lane);
                short8 blf = ldfrag(vl + (size_t)(df * 16) * NSRC + j0 + jc * 32, NSRC, lane);
                #pragma unroll
                for (int i = 0; i < 4; ++i) {
                    o[i][df] = mfma16(pa[i], bhf, o[i][df]);
                    o[i][df] = mfma16(pa[i], blf, o[i][df]);
                }
            }
        }
        __syncthreads();
    }
    // ---- rowsum: reduce within wave (across the 16 key-columns) ----
    #pragma unroll
    for (int i = 0; i < 4; ++i)
        #pragma unroll
        for (int r = 0; r < 4; ++r) {
            float v = rsum[i][r];
            v += __shfl_xor(v, 1, 64); v += __shfl_xor(v, 2, 64);
            v += __shfl_xor(v, 4, 64); v += __shfl_xor(v, 8, 64);
            if ((lane & 15) == 0) rsums[wave][i * 16 + (lane >> 4) * 4 + r] = v;
        }
    // ---- cross-wave reduction of o (each wave holds a disjoint key-quarter)
    float* redo = (float*)&pbuf[0][0];
    for (int w = 0; w < 4; ++w) {
        if (wave == w) {
            #pragma unroll
            for (int i = 0; i < 4; ++i)
                #pragma unroll
                for (int df = 0; df < 4; ++df)
                    #pragma unroll
                    for (int r = 0; r < 4; ++r) {
                        int row = i * 16 + (lane >> 4) * 4 + r;
                        int col = df * 16 + (lane & 15);
                        if (w == 0) redo[row * 68 + col] = o[i][df][r];
                        else        redo[row * 68 + col] += o[i][df][r];
                    }
        }
        __syncthreads();
    }
    if (threadIdx.x < 64) {
        float v = rsums[0][threadIdx.x] + rsums[1][threadIdx.x]
                + rsums[2][threadIdx.x] + rsums[3][threadIdx.x];
        rs[((size_t)split * (BATCH * NH) + bh) * NSINK + i0 + threadIdx.x] = v;
    }
    int b = bh >> 3, h = bh & 7;
    float* pvp = pv + (size_t)split * BATCH * NSINK * DIM;
    {
        int row = threadIdx.x >> 2, cb = (threadIdx.x & 3) * 16;
        float* dst = &pvp[((size_t)(b * NSINK + i0 + row)) * DIM + h * HD + cb];
        #pragma unroll
        for (int jj = 0; jj < 16; ++jj) dst[jj] = redo[row * 68 + cb + jj];
    }
}

// ---------------- finalize: a = (pv0+pv1+eps*vsum)/(rs0+rs1+Neps) -> split bf16 ----------------
__global__ __launch_bounds__(256) void finalize_pv(const float* __restrict__ pv,
    const float* __restrict__ rs, const float* __restrict__ vs,
    u16* __restrict__ ah, u16* __restrict__ al)
{
    int idx = blockIdx.x * 256 + threadIdx.x;
    int m = idx >> 9, n = idx & 511;
    int b = m >> 10, i = m & 1023, h = n >> 6, d = n & 63;
    int bh = b * NH + h;
    float val = pv[idx] + pv[idx + BATCH * NSINK * DIM] + EPS * vs[bh * HD + d];
    val /= (rs[bh * NSINK + i] + rs[BATCH * NH * NSINK + bh * NSINK + i] + (float)NSRC * EPS);
    u16 hh = f2bf(val);
    ah[idx] = hh;
    al[idx] = f2bf(val - bf2f(hh));
}

extern "C" void kernel_launch(void* const* d_in, const int* in_sizes, int n_in,
                              void* d_out, int out_size, void* d_ws, size_t ws_size,
                              hipStream_t stream) {
    (void)in_sizes; (void)n_in; (void)out_size;
    const float* sink    = (const float*)d_in[0];
    const float* source  = (const float*)d_in[1];
    const float* gamma_s = (const float*)d_in[2];
    const float* beta_s  = (const float*)d_in[3];
    const float* gamma_c = (const float*)d_in[4];
    const float* beta_c  = (const float*)d_in[5];
    const float* Wq      = (const float*)d_in[6];
    const float* bq      = (const float*)d_in[7];
    const float* Wkv     = (const float*)d_in[8];
    const float* bkv     = (const float*)d_in[9];
    const float* Wo      = (const float*)d_in[10];
    const float* bo      = (const float*)d_in[11];
    float* out = (float*)d_out;

    char* p = (char*)d_ws;
    auto carve = [&](size_t bytes) { char* r = p; p += (bytes + 255) & ~(size_t)255; return r; };
    u16* sh    = (u16*)carve(2048ull * 512 * 2);
    u16* sl    = (u16*)carve(2048ull * 512 * 2);
    u16* ch    = (u16*)carve(8192ull * 512 * 2);
    u16* cl    = (u16*)carve(8192ull * 512 * 2);
    u16* wqTh  = (u16*)carve(512ull * 512 * 2);
    u16* wqTl  = (u16*)carve(512ull * 512 * 2);
    u16* wkvTh = (u16*)carve(1024ull * 512 * 2);
    u16* wkvTl = (u16*)carve(1024ull * 512 * 2);
    u16* woTh  = (u16*)carve(512ull * 512 * 2);
    u16* woTl  = (u16*)carve(512ull * 512 * 2);
    u16* qb    = (u16*)carve(16ull * 1024 * 64 * 2);
    u16* kb    = (u16*)carve(16ull * 4096 * 64 * 2);
    u16* vTh   = (u16*)carve(16ull * 64 * 4096 * 2);
    u16* vTl   = (u16*)carve(16ull * 64 * 4096 * 2);
    float* colsum = (float*)carve(16ull * 4096 * 4);
    float* vs     = (float*)carve(1024ull * 4);
    float* pv     = (float*)carve(2ull * 2048 * 512 * 4);
    float* rs     = (float*)carve(2ull * 16 * 1024 * 4);
    u16* ah    = (u16*)carve(2048ull * 512 * 2);
    u16* al    = (u16*)carve(2048ull * 512 * 2);
    if ((size_t)(p - (char*)d_ws) > ws_size) return;

    ln_split<<<BATCH * NSINK, 256, 0, stream>>>(sink, gamma_s, beta_s, sh, sl);
    ln_split<<<BATCH * NSRC,  256, 0, stream>>>(source, gamma_c, beta_c, ch, cl);
    wt_split<<<512,  256, 0, stream>>>(Wq, 512, 512, wqTh, wqTl);
    wt_split<<<1024, 256, 0, stream>>>(Wkv, 512, 1024, wkvTh, wkvTl);
    wt_split<<<512,  256, 0, stream>>>(Wo, 512, 512, woTh, woTl);

    // Q: 1-term, 64x64 tiles -> 256 blocks
    gemm_lds<1, 64, 64><<<dim3(DIM / 64, BATCH * NSINK / 64), 256, 0, stream>>>(
        sh, nullptr, wqTh, nullptr, bq, 512, nullptr, qb, nullptr, nullptr);
    // KV: mixed 1/3-term, 128x128 tiles -> 512 blocks
    gemm_lds<2, 128, 128><<<dim3(2 * DIM / 128, BATCH * NSRC / 128), 256, 0, stream>>>(
        ch, cl, wkvTh, wkvTl, bkv, 512, nullptr, kb, vTh, vTl);

    vsum_k<<<1024, 256, 0, stream>>>(vTh, vTl, vs);
    pass_a<<<dim3(16, 16), 256, 0, stream>>>(qb, kb, colsum);
    pass_b<<<dim3(16, 2, 16), 256, 0, stream>>>(qb, kb, vTh, vTl, colsum, pv, rs);
    finalize_pv<<<4096, 256, 0, stream>>>(pv, rs, vs, ah, al);

    // out: 3-term, 64x64 tiles -> 256 blocks
    gemm_lds<0, 64, 64><<<dim3(DIM / 64, BATCH * NSINK / 64), 256, 0, stream>>>(
        ah, al, woTh, woTl, bo, 512, out, nullptr, nullptr, nullptr);
}